// Round 9
// baseline (483.436 us; speedup 1.0000x reference)
//
#include <hip/hip_runtime.h>

// ---------------------------------------------------------------------------
// 2-layer hetero GraphSAGE, bf16-MFMA.
// R15: - Algebraic restructure of the SONG side using mean/linear
//        commutation: mean_s(x@W) = mean_s(x)@W. Per layer:
//          OLD: gemm(yp=x_play@Wl) -> gemm(Gs=xs@Wr+b) -> agg(gather yp,
//               +Gs 25.6MB read, relu)            [3 dispatches]
//          NEW: agg(Msong=mean_s(x_play), pure mean, L2-resident src)
//               -> gemm2(s1=relu(Msong@Wl + xs@Wr + b))  [2 dispatches]
//        Kills both yp GEMMs, both Gs GEMMs + 25.6MB round-trips; fewer
//        bf16 rounding points than before. ALL four GEMMs are now the
//        R14-validated K=256 gemm2_breg_k.
//      - Playlist side unchanged from R14 (aggP -> gemm2).
//      - Base: XCD-chunked fixed-cap CSR build (47us atomic-rate floor,
//        R13), quad-group agg (R6), all-serial dispatches (R12 lesson).
//      - 10 dispatches: prep, build, aggS(Msong1), aggP(Ms1), gemm2(s1),
//        gemm2(p1), aggS(Msong2), aggP(Ms2), gemm2(s2), gemm2(p2).
// ---------------------------------------------------------------------------

typedef __attribute__((ext_vector_type(8))) short bfrag;   // 8 bf16 (4 VGPRs)
typedef __attribute__((ext_vector_type(4))) float ffrag;   // 4 fp32 acc
typedef unsigned short u16;
typedef unsigned int u32;

#define CAP_P 64   // max playlist degree guard (Binomial mean 25, max ~47)
#define CAP_S 32   // max song degree guard (Binomial mean 5, max ~20)

static inline size_t ws_align(size_t x) { return (x + 255) & ~size_t(255); }

__device__ inline u16 f2bf(float f) {
  union { float f; u32 u; } v; v.f = f;
  u32 r = v.u + 0x7fffu + ((v.u >> 16) & 1u);   // round-nearest-even
  return (u16)(r >> 16);
}
__device__ inline u32 pack2(float a, float b) {
  return (u32)f2bf(a) | ((u32)f2bf(b) << 16);
}
__device__ inline float bf_lo(u32 p) {
  union { u32 u; float f; } v; v.u = p << 16; return v.f;
}
__device__ inline float bf_hi(u32 p) {
  union { u32 u; float f; } v; v.u = p & 0xffff0000u; return v.f;
}

// ---- prep: zero counters, weight transpose+cast, song cast, playlist gather
__global__ __launch_bounds__(256) void prep_k(
    const float* __restrict__ w0, const float* __restrict__ w1,
    const float* __restrict__ w2, const float* __restrict__ w3,
    const float* __restrict__ w4, const float* __restrict__ w5,
    const float* __restrict__ w6, const float* __restrict__ w7,
    u16* __restrict__ Wt,
    const float* __restrict__ song_x, u16* __restrict__ xs, int ns4,
    const float* __restrict__ emb, const int* __restrict__ pid,
    u16* __restrict__ xp, int np,
    int* __restrict__ zero_region, int nzero)
{
  int g0 = blockIdx.x * 256 + threadIdx.x;
  int gs = gridDim.x * 256;
  for (int i = g0; i < nzero; i += gs) zero_region[i] = 0;
  const float* ws[8] = {w0, w1, w2, w3, w4, w5, w6, w7};
  for (int idx = g0; idx < 8 * 16384; idx += gs) {
    int m = idx >> 14, rem = idx & 16383;
    int n = rem >> 7, k = rem & 127;
    Wt[idx] = f2bf(ws[m][k * 128 + n]);
  }
  for (int i = g0; i < ns4; i += gs) {
    float4 v = ((const float4*)song_x)[i];
    ushort4 o;
    o.x = f2bf(v.x); o.y = f2bf(v.y); o.z = f2bf(v.z); o.w = f2bf(v.w);
    ((ushort4*)xs)[i] = o;
  }
  for (int i = g0; i < np * 32; i += gs) {
    int node = i >> 5, q = i & 31;
    float4 v = ((const float4*)(emb + (size_t)pid[node] * 128))[q];
    ushort4 o;
    o.x = f2bf(v.x); o.y = f2bf(v.y); o.z = f2bf(v.z); o.w = f2bf(v.w);
    ((ushort4*)(xp + (size_t)node * 128))[q] = o;
  }
}

// ---- fixed-capacity CSR build, XCD-chunked ---------------------------------
__global__ __launch_bounds__(256) void build_k(
    const int* __restrict__ es, const int* __restrict__ ep,
    int* __restrict__ cnt_s, int* __restrict__ cnt_p,
    int* __restrict__ csr_s, int* __restrict__ csr_p,
    int e, int pch, int sch)
{
  int j = blockIdx.x & 7;
  int g = blockIdx.x >> 3;
  int nb = gridDim.x >> 3;
  int p_lo = j * pch, s_lo = j * sch;
  int e4 = e >> 2;
  int gs = nb * 256;
  for (int i = g * 256 + threadIdx.x; i < e4; i += gs) {
    int4 p4 = ((const int4*)ep)[i];
    int4 s4 = ((const int4*)es)[i];
    if ((u32)(p4.x - p_lo) < (u32)pch) {
      int a = atomicAdd(&cnt_p[p4.x], 1);
      if (a < CAP_P) csr_p[p4.x * CAP_P + a] = s4.x;
    }
    if ((u32)(p4.y - p_lo) < (u32)pch) {
      int a = atomicAdd(&cnt_p[p4.y], 1);
      if (a < CAP_P) csr_p[p4.y * CAP_P + a] = s4.y;
    }
    if ((u32)(p4.z - p_lo) < (u32)pch) {
      int a = atomicAdd(&cnt_p[p4.z], 1);
      if (a < CAP_P) csr_p[p4.z * CAP_P + a] = s4.z;
    }
    if ((u32)(p4.w - p_lo) < (u32)pch) {
      int a = atomicAdd(&cnt_p[p4.w], 1);
      if (a < CAP_P) csr_p[p4.w * CAP_P + a] = s4.w;
    }
    if ((u32)(s4.x - s_lo) < (u32)sch) {
      int a = atomicAdd(&cnt_s[s4.x], 1);
      if (a < CAP_S) csr_s[s4.x * CAP_S + a] = p4.x;
    }
    if ((u32)(s4.y - s_lo) < (u32)sch) {
      int a = atomicAdd(&cnt_s[s4.y], 1);
      if (a < CAP_S) csr_s[s4.y * CAP_S + a] = p4.y;
    }
    if ((u32)(s4.z - s_lo) < (u32)sch) {
      int a = atomicAdd(&cnt_s[s4.z], 1);
      if (a < CAP_S) csr_s[s4.z * CAP_S + a] = p4.z;
    }
    if ((u32)(s4.w - s_lo) < (u32)sch) {
      int a = atomicAdd(&cnt_s[s4.w], 1);
      if (a < CAP_S) csr_s[s4.w * CAP_S + a] = p4.w;
    }
  }
  if (g == 0 && threadIdx.x == 0) {
    for (int i = e4 << 2; i < e; i++) {
      int p = ep[i], s = es[i];
      if ((u32)(p - p_lo) < (u32)pch) {
        int a = atomicAdd(&cnt_p[p], 1);
        if (a < CAP_P) csr_p[p * CAP_P + a] = s;
      }
      if ((u32)(s - s_lo) < (u32)sch) {
        int a = atomicAdd(&cnt_s[s], 1);
        if (a < CAP_S) csr_s[s * CAP_S + a] = p;
      }
    }
  }
}

// ---- quad-group PURE mean aggregation, fixed-stride CSR --------------------
// One 16-lane group per dst row; rounds of 8 predicated independent gathers.
// out[v] = mean_{u in csr[v]} feat[u]  (bf16 out).
__global__ __launch_bounds__(256) void agg_mean_k(
    const u16* __restrict__ feat, const int* __restrict__ csr, int cap,
    const int* __restrict__ cnt, u16* __restrict__ out, int n)
{
  int lr = threadIdx.x & 15;
  int grp = threadIdx.x >> 4;           // 0..15
  int gv = blockIdx.x * 16 + grp;
  if (gv >= n) return;
  int b = gv * cap;
  int c = cnt[gv];
  int cm = min(c, cap);
  float s0=0,s1=0,s2=0,s3=0,s4=0,s5=0,s6=0,s7=0;
  for (int i = 0; i < cm; i += 8) {
    int m = cm - i;
    int idx[8];
#pragma unroll
    for (int u = 0; u < 8; u++) idx[u] = csr[b + i + min(u, m - 1)];
#pragma unroll
    for (int u = 0; u < 8; u++) {
      uint4 v = ((const uint4*)(feat + (size_t)idx[u] * 128))[lr];
      if (u < m) {
        s0 += bf_lo(v.x); s1 += bf_hi(v.x);
        s2 += bf_lo(v.y); s3 += bf_hi(v.y);
        s4 += bf_lo(v.z); s5 += bf_hi(v.z);
        s6 += bf_lo(v.w); s7 += bf_hi(v.w);
      }
    }
  }
  float inv = (c > 0) ? 1.0f / (float)c : 0.0f;
  uint4 o;
  o.x = pack2(s0 * inv, s1 * inv);
  o.y = pack2(s2 * inv, s3 * inv);
  o.z = pack2(s4 * inv, s5 * inv);
  o.w = pack2(s6 * inv, s7 * inv);
  ((uint4*)(out + (size_t)gv * 128))[lr] = o;
}

// ---- K=256 fused GEMM: C[M,128] = act( A1@W1 + A2@W2 + bias ) -------------
// B-frags reloaded per K-half inside the strip loop (#pragma unroll 1 keeps
// ONE 128-VGPR B set live -> occupancy same as single-K gemm).
__global__ __launch_bounds__(256, 2) void gemm2_breg_k(
    const u16* __restrict__ A1, const u16* __restrict__ W1,
    const u16* __restrict__ A2, const u16* __restrict__ W2,
    const float* __restrict__ bias,
    void* __restrict__ Cout, int M, int doRelu, int outF32)
{
  int lane = threadIdx.x & 63;
  int r = lane & 15, q = lane >> 4;
  int wid = (blockIdx.x * 256 + threadIdx.x) >> 6;
  int nw = gridDim.x * 4;
  const u16* As[2] = {A1, A2};
  const u16* Ws[2] = {W1, W2};

  for (int strip = wid; strip * 16 < M; strip += nw) {
    ffrag acc[8];
#pragma unroll
    for (int j = 0; j < 8; j++) acc[j] = (ffrag)0.f;

#pragma unroll 1
    for (int h = 0; h < 2; h++) {
      const u16* arow = As[h] + (size_t)(strip * 16 + r) * 128 + q * 8;
      bfrag a0 = *(const bfrag*)(arow);
      bfrag a1 = *(const bfrag*)(arow + 32);
      bfrag a2 = *(const bfrag*)(arow + 64);
      bfrag a3 = *(const bfrag*)(arow + 96);
      bfrag B[4][8];
#pragma unroll
      for (int k0 = 0; k0 < 4; k0++)
#pragma unroll
        for (int j = 0; j < 8; j++)
          B[k0][j] = *(const bfrag*)(Ws[h] + (size_t)(j * 16 + r) * 128 + k0 * 32 + q * 8);
#pragma unroll
      for (int j = 0; j < 8; j++)
        acc[j] = __builtin_amdgcn_mfma_f32_16x16x32_bf16(B[0][j], a0, acc[j], 0, 0, 0);
#pragma unroll
      for (int j = 0; j < 8; j++)
        acc[j] = __builtin_amdgcn_mfma_f32_16x16x32_bf16(B[1][j], a1, acc[j], 0, 0, 0);
#pragma unroll
      for (int j = 0; j < 8; j++)
        acc[j] = __builtin_amdgcn_mfma_f32_16x16x32_bf16(B[2][j], a2, acc[j], 0, 0, 0);
#pragma unroll
      for (int j = 0; j < 8; j++)
        acc[j] = __builtin_amdgcn_mfma_f32_16x16x32_bf16(B[3][j], a3, acc[j], 0, 0, 0);
    }

    size_t row = (size_t)(strip * 16 + r);
#pragma unroll
    for (int j = 0; j < 8; j++) {
      int col0 = j * 16 + q * 4;
      float v0 = acc[j][0], v1 = acc[j][1], v2 = acc[j][2], v3 = acc[j][3];
      if (bias) {
        float4 bv = *(const float4*)(bias + col0);
        v0 += bv.x; v1 += bv.y; v2 += bv.z; v3 += bv.w;
      }
      if (doRelu) {
        v0 = fmaxf(v0, 0.f); v1 = fmaxf(v1, 0.f);
        v2 = fmaxf(v2, 0.f); v3 = fmaxf(v3, 0.f);
      }
      if (outF32) {
        *(float4*)((float*)Cout + row * 128 + col0) = make_float4(v0, v1, v2, v3);
      } else {
        ushort4 o;
        o.x = f2bf(v0); o.y = f2bf(v1); o.z = f2bf(v2); o.w = f2bf(v3);
        *(ushort4*)((u16*)Cout + row * 128 + col0) = o;
      }
    }
  }
}

// ---------------------------------------------------------------------------

extern "C" void kernel_launch(void* const* d_in, const int* in_sizes, int n_in,
                              void* d_out, int out_size, void* d_ws, size_t ws_size,
                              hipStream_t stream)
{
  const float* song_x = (const float*)d_in[0];
  const int*   pid    = (const int*)d_in[1];
  const int*   e_song = (const int*)d_in[2];
  const int*   e_play = (const int*)d_in[3];
  const float* emb    = (const float*)d_in[4];
  const float* Wl1_sp = (const float*)d_in[5];
  const float* Wr1_sp = (const float*)d_in[6];
  const float* b1_sp  = (const float*)d_in[7];
  const float* Wl1_ps = (const float*)d_in[8];
  const float* Wr1_ps = (const float*)d_in[9];
  const float* b1_ps  = (const float*)d_in[10];
  const float* Wl2_sp = (const float*)d_in[11];
  const float* Wr2_sp = (const float*)d_in[12];
  const float* b2_sp  = (const float*)d_in[13];
  const float* Wl2_ps = (const float*)d_in[14];
  const float* Wr2_ps = (const float*)d_in[15];
  const float* b2_ps  = (const float*)d_in[16];

  const int NS = in_sizes[0] / 128;
  const int NP = in_sizes[1];
  const int E  = in_sizes[2];

  char* w = (char*)d_ws;
  auto alloc = [&](size_t bytes) { char* p = w; w += ws_align(bytes); return p; };
  u16* x_play = (u16*)alloc((size_t)NP * 128 * 2);
  u16* Ms     = (u16*)alloc((size_t)NP * 128 * 2);   // mean_p(...)  [NP,128]
  u16* p1     = (u16*)alloc((size_t)NP * 128 * 2);
  u16* s1     = (u16*)alloc((size_t)NS * 128 * 2);
  u16* xs     = (u16*)alloc((size_t)NS * 128 * 2);
  u16* Msong  = (u16*)alloc((size_t)NS * 128 * 2);   // mean_s(...)  [NS,128]
  u16* Wt     = (u16*)alloc((size_t)8 * 16384 * 2);  // [mat][n][k]
  int* cnt_p  = (int*)alloc(((size_t)NP + NS) * 4);
  int* cnt_s  = cnt_p + NP;
  int* csr_p  = (int*)alloc((size_t)NP * CAP_P * 4);
  int* csr_s  = (int*)alloc((size_t)NS * CAP_S * 4);

  float* s2_out = (float*)d_out;
  float* p2_out = (float*)d_out + (size_t)NS * 128;

  u16* Wt_l1sp = Wt + 0 * 16384;
  u16* Wt_r1sp = Wt + 1 * 16384;
  u16* Wt_l1ps = Wt + 2 * 16384;
  u16* Wt_r1ps = Wt + 3 * 16384;
  u16* Wt_l2sp = Wt + 4 * 16384;
  u16* Wt_r2sp = Wt + 5 * 16384;
  u16* Wt_l2ps = Wt + 6 * 16384;
  u16* Wt_r2ps = Wt + 7 * 16384;

  auto ggrid = [](int M) { int s = M / 16; return (s + 7) / 8; };
  const int gP = ggrid(NP), gS = ggrid(NS);
  const int aggP_b = (NP + 15) / 16, aggS_b = (NS + 15) / 16;
  const int pch = (NP + 7) / 8, sch = (NS + 7) / 8;

  // ---- prep (also zeros degree counters) ----
  prep_k<<<1024, 256, 0, stream>>>(Wl1_sp, Wr1_sp, Wl1_ps, Wr1_ps,
                                   Wl2_sp, Wr2_sp, Wl2_ps, Wr2_ps, Wt,
                                   song_x, xs, NS * 32,
                                   emb, pid, x_play, NP,
                                   cnt_p, NP + NS);

  // ---- CSR build (XCD-chunked atomic wall; standalone) ----
  build_k<<<1024, 256, 0, stream>>>(e_song, e_play, cnt_s, cnt_p,
                                    csr_s, csr_p, E, pch, sch);

  // ---- layer 1 ----
  // Msong1 = mean_s(x_play)   (gather source 5MB, L2-resident)
  agg_mean_k<<<aggS_b, 256, 0, stream>>>(x_play, csr_s, CAP_S, cnt_s,
                                         Msong, NS);
  // Ms1 = mean_p(xs)
  agg_mean_k<<<aggP_b, 256, 0, stream>>>(xs, csr_p, CAP_P, cnt_p,
                                         Ms, NP);
  // s1 = relu(Msong1@Wl1_ps + xs@Wr1_ps + b1_ps)   [K=256]
  gemm2_breg_k<<<gS, 256, 0, stream>>>(Msong, Wt_l1ps, xs, Wt_r1ps,
                                       b1_ps, s1, NS, 1, 0);
  // p1 = relu(Ms1@Wl1_sp + x_play@Wr1_sp + b1_sp)  [K=256]
  gemm2_breg_k<<<gP, 256, 0, stream>>>(Ms, Wt_l1sp, x_play, Wt_r1sp,
                                       b1_sp, p1, NP, 1, 0);

  // ---- layer 2 ----
  // Msong2 = mean_s(p1)
  agg_mean_k<<<aggS_b, 256, 0, stream>>>(p1, csr_s, CAP_S, cnt_s,
                                         Msong, NS);
  // Ms2 = mean_p(s1)
  agg_mean_k<<<aggP_b, 256, 0, stream>>>(s1, csr_p, CAP_P, cnt_p,
                                         Ms, NP);
  // s2 = Msong2@Wl2_ps + s1@Wr2_ps + b2_ps  (f32 out)
  gemm2_breg_k<<<gS, 256, 0, stream>>>(Msong, Wt_l2ps, s1, Wt_r2ps,
                                       b2_ps, s2_out, NS, 0, 1);
  // p2 = Ms2@Wl2_sp + p1@Wr2_sp + b2_sp  (f32 out)
  gemm2_breg_k<<<gP, 256, 0, stream>>>(Ms, Wt_l2sp, p1, Wt_r2sp,
                                       b2_sp, p2_out, NP, 0, 1);
}

// Round 10
// 462.077 us; speedup vs baseline: 1.0462x; 1.0462x over previous
//
#include <hip/hip_runtime.h>

// ---------------------------------------------------------------------------
// 2-layer hetero GraphSAGE, bf16-MFMA.
// R16: - R15 structure kept (mean/linear commutation, all GEMMs = K=256
//        gemm2; 10 dispatches). R15's 483us regression was a GRID bug:
//        gemm2 reloads B per strip (B traffic is grid-independent), but
//        I kept the B-persistent kernel's small grid (8 strips/wave) ->
//        3 blocks/CU, 25% occupancy, serialized B-load->MFMA chains
//        (77us @ MfmaUtil 3%). Fix: ONE STRIP PER WAVE grid
//        (ceil(strips/4) blocks) -> ~6 blocks/CU, ~75% occupancy, same
//        total traffic. launch_bounds(256) (drop min-2).
//      - Base: XCD-chunked fixed-cap CSR build (47us atomic-rate floor),
//        quad-group pure-mean agg, all-serial dispatches.
// ---------------------------------------------------------------------------

typedef __attribute__((ext_vector_type(8))) short bfrag;   // 8 bf16 (4 VGPRs)
typedef __attribute__((ext_vector_type(4))) float ffrag;   // 4 fp32 acc
typedef unsigned short u16;
typedef unsigned int u32;

#define CAP_P 64   // max playlist degree guard (Binomial mean 25, max ~47)
#define CAP_S 32   // max song degree guard (Binomial mean 5, max ~20)

static inline size_t ws_align(size_t x) { return (x + 255) & ~size_t(255); }

__device__ inline u16 f2bf(float f) {
  union { float f; u32 u; } v; v.f = f;
  u32 r = v.u + 0x7fffu + ((v.u >> 16) & 1u);   // round-nearest-even
  return (u16)(r >> 16);
}
__device__ inline u32 pack2(float a, float b) {
  return (u32)f2bf(a) | ((u32)f2bf(b) << 16);
}
__device__ inline float bf_lo(u32 p) {
  union { u32 u; float f; } v; v.u = p << 16; return v.f;
}
__device__ inline float bf_hi(u32 p) {
  union { u32 u; float f; } v; v.u = p & 0xffff0000u; return v.f;
}

// ---- prep: zero counters, weight transpose+cast, song cast, playlist gather
__global__ __launch_bounds__(256) void prep_k(
    const float* __restrict__ w0, const float* __restrict__ w1,
    const float* __restrict__ w2, const float* __restrict__ w3,
    const float* __restrict__ w4, const float* __restrict__ w5,
    const float* __restrict__ w6, const float* __restrict__ w7,
    u16* __restrict__ Wt,
    const float* __restrict__ song_x, u16* __restrict__ xs, int ns4,
    const float* __restrict__ emb, const int* __restrict__ pid,
    u16* __restrict__ xp, int np,
    int* __restrict__ zero_region, int nzero)
{
  int g0 = blockIdx.x * 256 + threadIdx.x;
  int gs = gridDim.x * 256;
  for (int i = g0; i < nzero; i += gs) zero_region[i] = 0;
  const float* ws[8] = {w0, w1, w2, w3, w4, w5, w6, w7};
  for (int idx = g0; idx < 8 * 16384; idx += gs) {
    int m = idx >> 14, rem = idx & 16383;
    int n = rem >> 7, k = rem & 127;
    Wt[idx] = f2bf(ws[m][k * 128 + n]);
  }
  for (int i = g0; i < ns4; i += gs) {
    float4 v = ((const float4*)song_x)[i];
    ushort4 o;
    o.x = f2bf(v.x); o.y = f2bf(v.y); o.z = f2bf(v.z); o.w = f2bf(v.w);
    ((ushort4*)xs)[i] = o;
  }
  for (int i = g0; i < np * 32; i += gs) {
    int node = i >> 5, q = i & 31;
    float4 v = ((const float4*)(emb + (size_t)pid[node] * 128))[q];
    ushort4 o;
    o.x = f2bf(v.x); o.y = f2bf(v.y); o.z = f2bf(v.z); o.w = f2bf(v.w);
    ((ushort4*)(xp + (size_t)node * 128))[q] = o;
  }
}

// ---- fixed-capacity CSR build, XCD-chunked ---------------------------------
__global__ __launch_bounds__(256) void build_k(
    const int* __restrict__ es, const int* __restrict__ ep,
    int* __restrict__ cnt_s, int* __restrict__ cnt_p,
    int* __restrict__ csr_s, int* __restrict__ csr_p,
    int e, int pch, int sch)
{
  int j = blockIdx.x & 7;
  int g = blockIdx.x >> 3;
  int nb = gridDim.x >> 3;
  int p_lo = j * pch, s_lo = j * sch;
  int e4 = e >> 2;
  int gs = nb * 256;
  for (int i = g * 256 + threadIdx.x; i < e4; i += gs) {
    int4 p4 = ((const int4*)ep)[i];
    int4 s4 = ((const int4*)es)[i];
    if ((u32)(p4.x - p_lo) < (u32)pch) {
      int a = atomicAdd(&cnt_p[p4.x], 1);
      if (a < CAP_P) csr_p[p4.x * CAP_P + a] = s4.x;
    }
    if ((u32)(p4.y - p_lo) < (u32)pch) {
      int a = atomicAdd(&cnt_p[p4.y], 1);
      if (a < CAP_P) csr_p[p4.y * CAP_P + a] = s4.y;
    }
    if ((u32)(p4.z - p_lo) < (u32)pch) {
      int a = atomicAdd(&cnt_p[p4.z], 1);
      if (a < CAP_P) csr_p[p4.z * CAP_P + a] = s4.z;
    }
    if ((u32)(p4.w - p_lo) < (u32)pch) {
      int a = atomicAdd(&cnt_p[p4.w], 1);
      if (a < CAP_P) csr_p[p4.w * CAP_P + a] = s4.w;
    }
    if ((u32)(s4.x - s_lo) < (u32)sch) {
      int a = atomicAdd(&cnt_s[s4.x], 1);
      if (a < CAP_S) csr_s[s4.x * CAP_S + a] = p4.x;
    }
    if ((u32)(s4.y - s_lo) < (u32)sch) {
      int a = atomicAdd(&cnt_s[s4.y], 1);
      if (a < CAP_S) csr_s[s4.y * CAP_S + a] = p4.y;
    }
    if ((u32)(s4.z - s_lo) < (u32)sch) {
      int a = atomicAdd(&cnt_s[s4.z], 1);
      if (a < CAP_S) csr_s[s4.z * CAP_S + a] = p4.z;
    }
    if ((u32)(s4.w - s_lo) < (u32)sch) {
      int a = atomicAdd(&cnt_s[s4.w], 1);
      if (a < CAP_S) csr_s[s4.w * CAP_S + a] = p4.w;
    }
  }
  if (g == 0 && threadIdx.x == 0) {
    for (int i = e4 << 2; i < e; i++) {
      int p = ep[i], s = es[i];
      if ((u32)(p - p_lo) < (u32)pch) {
        int a = atomicAdd(&cnt_p[p], 1);
        if (a < CAP_P) csr_p[p * CAP_P + a] = s;
      }
      if ((u32)(s - s_lo) < (u32)sch) {
        int a = atomicAdd(&cnt_s[s], 1);
        if (a < CAP_S) csr_s[s * CAP_S + a] = p;
      }
    }
  }
}

// ---- quad-group PURE mean aggregation, fixed-stride CSR --------------------
__global__ __launch_bounds__(256) void agg_mean_k(
    const u16* __restrict__ feat, const int* __restrict__ csr, int cap,
    const int* __restrict__ cnt, u16* __restrict__ out, int n)
{
  int lr = threadIdx.x & 15;
  int grp = threadIdx.x >> 4;           // 0..15
  int gv = blockIdx.x * 16 + grp;
  if (gv >= n) return;
  int b = gv * cap;
  int c = cnt[gv];
  int cm = min(c, cap);
  float s0=0,s1=0,s2=0,s3=0,s4=0,s5=0,s6=0,s7=0;
  for (int i = 0; i < cm; i += 8) {
    int m = cm - i;
    int idx[8];
#pragma unroll
    for (int u = 0; u < 8; u++) idx[u] = csr[b + i + min(u, m - 1)];
#pragma unroll
    for (int u = 0; u < 8; u++) {
      uint4 v = ((const uint4*)(feat + (size_t)idx[u] * 128))[lr];
      if (u < m) {
        s0 += bf_lo(v.x); s1 += bf_hi(v.x);
        s2 += bf_lo(v.y); s3 += bf_hi(v.y);
        s4 += bf_lo(v.z); s5 += bf_hi(v.z);
        s6 += bf_lo(v.w); s7 += bf_hi(v.w);
      }
    }
  }
  float inv = (c > 0) ? 1.0f / (float)c : 0.0f;
  uint4 o;
  o.x = pack2(s0 * inv, s1 * inv);
  o.y = pack2(s2 * inv, s3 * inv);
  o.z = pack2(s4 * inv, s5 * inv);
  o.w = pack2(s6 * inv, s7 * inv);
  ((uint4*)(out + (size_t)gv * 128))[lr] = o;
}

// ---- K=256 fused GEMM: C[M,128] = act( A1@W1 + A2@W2 + bias ) -------------
// B reloaded per K-half per strip (grid-independent B traffic). Launch with
// ONE STRIP PER WAVE (grid = ceil(M/16/4)) for max occupancy/TLP.
__global__ __launch_bounds__(256) void gemm2_breg_k(
    const u16* __restrict__ A1, const u16* __restrict__ W1,
    const u16* __restrict__ A2, const u16* __restrict__ W2,
    const float* __restrict__ bias,
    void* __restrict__ Cout, int M, int doRelu, int outF32)
{
  int lane = threadIdx.x & 63;
  int r = lane & 15, q = lane >> 4;
  int wid = (blockIdx.x * 256 + threadIdx.x) >> 6;
  int nw = gridDim.x * 4;
  const u16* As[2] = {A1, A2};
  const u16* Ws[2] = {W1, W2};

  for (int strip = wid; strip * 16 < M; strip += nw) {
    ffrag acc[8];
#pragma unroll
    for (int j = 0; j < 8; j++) acc[j] = (ffrag)0.f;

#pragma unroll 1
    for (int h = 0; h < 2; h++) {
      const u16* arow = As[h] + (size_t)(strip * 16 + r) * 128 + q * 8;
      bfrag a0 = *(const bfrag*)(arow);
      bfrag a1 = *(const bfrag*)(arow + 32);
      bfrag a2 = *(const bfrag*)(arow + 64);
      bfrag a3 = *(const bfrag*)(arow + 96);
      bfrag B[4][8];
#pragma unroll
      for (int k0 = 0; k0 < 4; k0++)
#pragma unroll
        for (int j = 0; j < 8; j++)
          B[k0][j] = *(const bfrag*)(Ws[h] + (size_t)(j * 16 + r) * 128 + k0 * 32 + q * 8);
#pragma unroll
      for (int j = 0; j < 8; j++)
        acc[j] = __builtin_amdgcn_mfma_f32_16x16x32_bf16(B[0][j], a0, acc[j], 0, 0, 0);
#pragma unroll
      for (int j = 0; j < 8; j++)
        acc[j] = __builtin_amdgcn_mfma_f32_16x16x32_bf16(B[1][j], a1, acc[j], 0, 0, 0);
#pragma unroll
      for (int j = 0; j < 8; j++)
        acc[j] = __builtin_amdgcn_mfma_f32_16x16x32_bf16(B[2][j], a2, acc[j], 0, 0, 0);
#pragma unroll
      for (int j = 0; j < 8; j++)
        acc[j] = __builtin_amdgcn_mfma_f32_16x16x32_bf16(B[3][j], a3, acc[j], 0, 0, 0);
    }

    size_t row = (size_t)(strip * 16 + r);
#pragma unroll
    for (int j = 0; j < 8; j++) {
      int col0 = j * 16 + q * 4;
      float v0 = acc[j][0], v1 = acc[j][1], v2 = acc[j][2], v3 = acc[j][3];
      if (bias) {
        float4 bv = *(const float4*)(bias + col0);
        v0 += bv.x; v1 += bv.y; v2 += bv.z; v3 += bv.w;
      }
      if (doRelu) {
        v0 = fmaxf(v0, 0.f); v1 = fmaxf(v1, 0.f);
        v2 = fmaxf(v2, 0.f); v3 = fmaxf(v3, 0.f);
      }
      if (outF32) {
        *(float4*)((float*)Cout + row * 128 + col0) = make_float4(v0, v1, v2, v3);
      } else {
        ushort4 o;
        o.x = f2bf(v0); o.y = f2bf(v1); o.z = f2bf(v2); o.w = f2bf(v3);
        *(ushort4*)((u16*)Cout + row * 128 + col0) = o;
      }
    }
  }
}

// ---------------------------------------------------------------------------

extern "C" void kernel_launch(void* const* d_in, const int* in_sizes, int n_in,
                              void* d_out, int out_size, void* d_ws, size_t ws_size,
                              hipStream_t stream)
{
  const float* song_x = (const float*)d_in[0];
  const int*   pid    = (const int*)d_in[1];
  const int*   e_song = (const int*)d_in[2];
  const int*   e_play = (const int*)d_in[3];
  const float* emb    = (const float*)d_in[4];
  const float* Wl1_sp = (const float*)d_in[5];
  const float* Wr1_sp = (const float*)d_in[6];
  const float* b1_sp  = (const float*)d_in[7];
  const float* Wl1_ps = (const float*)d_in[8];
  const float* Wr1_ps = (const float*)d_in[9];
  const float* b1_ps  = (const float*)d_in[10];
  const float* Wl2_sp = (const float*)d_in[11];
  const float* Wr2_sp = (const float*)d_in[12];
  const float* b2_sp  = (const float*)d_in[13];
  const float* Wl2_ps = (const float*)d_in[14];
  const float* Wr2_ps = (const float*)d_in[15];
  const float* b2_ps  = (const float*)d_in[16];

  const int NS = in_sizes[0] / 128;
  const int NP = in_sizes[1];
  const int E  = in_sizes[2];

  char* w = (char*)d_ws;
  auto alloc = [&](size_t bytes) { char* p = w; w += ws_align(bytes); return p; };
  u16* x_play = (u16*)alloc((size_t)NP * 128 * 2);
  u16* Ms     = (u16*)alloc((size_t)NP * 128 * 2);   // mean_p(...)  [NP,128]
  u16* p1     = (u16*)alloc((size_t)NP * 128 * 2);
  u16* s1     = (u16*)alloc((size_t)NS * 128 * 2);
  u16* xs     = (u16*)alloc((size_t)NS * 128 * 2);
  u16* Msong  = (u16*)alloc((size_t)NS * 128 * 2);   // mean_s(...)  [NS,128]
  u16* Wt     = (u16*)alloc((size_t)8 * 16384 * 2);  // [mat][n][k]
  int* cnt_p  = (int*)alloc(((size_t)NP + NS) * 4);
  int* cnt_s  = cnt_p + NP;
  int* csr_p  = (int*)alloc((size_t)NP * CAP_P * 4);
  int* csr_s  = (int*)alloc((size_t)NS * CAP_S * 4);

  float* s2_out = (float*)d_out;
  float* p2_out = (float*)d_out + (size_t)NS * 128;

  u16* Wt_l1sp = Wt + 0 * 16384;
  u16* Wt_r1sp = Wt + 1 * 16384;
  u16* Wt_l1ps = Wt + 2 * 16384;
  u16* Wt_r1ps = Wt + 3 * 16384;
  u16* Wt_l2sp = Wt + 4 * 16384;
  u16* Wt_r2sp = Wt + 5 * 16384;
  u16* Wt_l2ps = Wt + 6 * 16384;
  u16* Wt_r2ps = Wt + 7 * 16384;

  // one strip per wave: grid = ceil(M/16/4)
  auto g2grid = [](int M) { int s = (M + 15) / 16; return (s + 3) / 4; };
  const int g2P = g2grid(NP), g2S = g2grid(NS);     // 313, 1563
  const int aggP_b = (NP + 15) / 16, aggS_b = (NS + 15) / 16;
  const int pch = (NP + 7) / 8, sch = (NS + 7) / 8;

  // ---- prep (also zeros degree counters) ----
  prep_k<<<1024, 256, 0, stream>>>(Wl1_sp, Wr1_sp, Wl1_ps, Wr1_ps,
                                   Wl2_sp, Wr2_sp, Wl2_ps, Wr2_ps, Wt,
                                   song_x, xs, NS * 32,
                                   emb, pid, x_play, NP,
                                   cnt_p, NP + NS);

  // ---- CSR build (XCD-chunked atomic wall; standalone) ----
  build_k<<<1024, 256, 0, stream>>>(e_song, e_play, cnt_s, cnt_p,
                                    csr_s, csr_p, E, pch, sch);

  // ---- layer 1 ----
  // Msong1 = mean_s(x_play)   (gather source 5MB, L2-resident)
  agg_mean_k<<<aggS_b, 256, 0, stream>>>(x_play, csr_s, CAP_S, cnt_s,
                                         Msong, NS);
  // Ms1 = mean_p(xs)
  agg_mean_k<<<aggP_b, 256, 0, stream>>>(xs, csr_p, CAP_P, cnt_p,
                                         Ms, NP);
  // s1 = relu(Msong1@Wl1_ps + xs@Wr1_ps + b1_ps)   [K=256]
  gemm2_breg_k<<<g2S, 256, 0, stream>>>(Msong, Wt_l1ps, xs, Wt_r1ps,
                                        b1_ps, s1, NS, 1, 0);
  // p1 = relu(Ms1@Wl1_sp + x_play@Wr1_sp + b1_sp)  [K=256]
  gemm2_breg_k<<<g2P, 256, 0, stream>>>(Ms, Wt_l1sp, x_play, Wt_r1sp,
                                        b1_sp, p1, NP, 1, 0);

  // ---- layer 2 ----
  // Msong2 = mean_s(p1)
  agg_mean_k<<<aggS_b, 256, 0, stream>>>(p1, csr_s, CAP_S, cnt_s,
                                         Msong, NS);
  // Ms2 = mean_p(s1)
  agg_mean_k<<<aggP_b, 256, 0, stream>>>(s1, csr_p, CAP_P, cnt_p,
                                         Ms, NP);
  // s2 = Msong2@Wl2_ps + s1@Wr2_ps + b2_ps  (f32 out)
  gemm2_breg_k<<<g2S, 256, 0, stream>>>(Msong, Wt_l2ps, s1, Wt_r2ps,
                                        b2_ps, s2_out, NS, 0, 1);
  // p2 = Ms2@Wl2_sp + p1@Wr2_sp + b2_sp  (f32 out)
  gemm2_breg_k<<<g2P, 256, 0, stream>>>(Ms, Wt_l2sp, p1, Wt_r2sp,
                                        b2_sp, p2_out, NP, 0, 1);
}

// Round 11
// 354.830 us; speedup vs baseline: 1.3624x; 1.3022x over previous
//
#include <hip/hip_runtime.h>

// ---------------------------------------------------------------------------
// 2-layer hetero GraphSAGE, bf16-MFMA.
// R17: - R15/16 algebra kept (mean/linear commutation; all GEMMs K=256).
//        R16's 72us S-gemm2 was B-reload-from-L2 bound: 64KB/wave/strip
//        (~400MB L2 traffic S-side) of serialized dependent loads.
//      - NEW gemm2_lds_k: both W matrices staged to LDS once per block
//        (64KB, 2 blocks/CU), B-frags via ds_read_b128 with the G4
//        XOR-swizzle byte^=((row&7)<<4) on store+read (our [128]x256B
//        b128 pattern == the verified attn K_lds case). row&7==r&7 ->
//        swizzle j-invariant -> one addr reg + offset: immediates.
//      - Base: XCD-chunked fixed-cap CSR build (47us atomic-rate floor),
//        quad-group pure-mean agg, all-serial dispatches. 10 dispatches.
// ---------------------------------------------------------------------------

typedef __attribute__((ext_vector_type(8))) short bfrag;   // 8 bf16 (4 VGPRs)
typedef __attribute__((ext_vector_type(4))) float ffrag;   // 4 fp32 acc
typedef unsigned short u16;
typedef unsigned int u32;

#define CAP_P 64   // max playlist degree guard (Binomial mean 25, max ~47)
#define CAP_S 32   // max song degree guard (Binomial mean 5, max ~20)

static inline size_t ws_align(size_t x) { return (x + 255) & ~size_t(255); }

__device__ inline u16 f2bf(float f) {
  union { float f; u32 u; } v; v.f = f;
  u32 r = v.u + 0x7fffu + ((v.u >> 16) & 1u);   // round-nearest-even
  return (u16)(r >> 16);
}
__device__ inline u32 pack2(float a, float b) {
  return (u32)f2bf(a) | ((u32)f2bf(b) << 16);
}
__device__ inline float bf_lo(u32 p) {
  union { u32 u; float f; } v; v.u = p << 16; return v.f;
}
__device__ inline float bf_hi(u32 p) {
  union { u32 u; float f; } v; v.u = p & 0xffff0000u; return v.f;
}

// ---- prep: zero counters, weight transpose+cast, song cast, playlist gather
__global__ __launch_bounds__(256) void prep_k(
    const float* __restrict__ w0, const float* __restrict__ w1,
    const float* __restrict__ w2, const float* __restrict__ w3,
    const float* __restrict__ w4, const float* __restrict__ w5,
    const float* __restrict__ w6, const float* __restrict__ w7,
    u16* __restrict__ Wt,
    const float* __restrict__ song_x, u16* __restrict__ xs, int ns4,
    const float* __restrict__ emb, const int* __restrict__ pid,
    u16* __restrict__ xp, int np,
    int* __restrict__ zero_region, int nzero)
{
  int g0 = blockIdx.x * 256 + threadIdx.x;
  int gs = gridDim.x * 256;
  for (int i = g0; i < nzero; i += gs) zero_region[i] = 0;
  const float* ws[8] = {w0, w1, w2, w3, w4, w5, w6, w7};
  for (int idx = g0; idx < 8 * 16384; idx += gs) {
    int m = idx >> 14, rem = idx & 16383;
    int n = rem >> 7, k = rem & 127;
    Wt[idx] = f2bf(ws[m][k * 128 + n]);
  }
  for (int i = g0; i < ns4; i += gs) {
    float4 v = ((const float4*)song_x)[i];
    ushort4 o;
    o.x = f2bf(v.x); o.y = f2bf(v.y); o.z = f2bf(v.z); o.w = f2bf(v.w);
    ((ushort4*)xs)[i] = o;
  }
  for (int i = g0; i < np * 32; i += gs) {
    int node = i >> 5, q = i & 31;
    float4 v = ((const float4*)(emb + (size_t)pid[node] * 128))[q];
    ushort4 o;
    o.x = f2bf(v.x); o.y = f2bf(v.y); o.z = f2bf(v.z); o.w = f2bf(v.w);
    ((ushort4*)(xp + (size_t)node * 128))[q] = o;
  }
}

// ---- fixed-capacity CSR build, XCD-chunked ---------------------------------
__global__ __launch_bounds__(256) void build_k(
    const int* __restrict__ es, const int* __restrict__ ep,
    int* __restrict__ cnt_s, int* __restrict__ cnt_p,
    int* __restrict__ csr_s, int* __restrict__ csr_p,
    int e, int pch, int sch)
{
  int j = blockIdx.x & 7;
  int g = blockIdx.x >> 3;
  int nb = gridDim.x >> 3;
  int p_lo = j * pch, s_lo = j * sch;
  int e4 = e >> 2;
  int gs = nb * 256;
  for (int i = g * 256 + threadIdx.x; i < e4; i += gs) {
    int4 p4 = ((const int4*)ep)[i];
    int4 s4 = ((const int4*)es)[i];
    if ((u32)(p4.x - p_lo) < (u32)pch) {
      int a = atomicAdd(&cnt_p[p4.x], 1);
      if (a < CAP_P) csr_p[p4.x * CAP_P + a] = s4.x;
    }
    if ((u32)(p4.y - p_lo) < (u32)pch) {
      int a = atomicAdd(&cnt_p[p4.y], 1);
      if (a < CAP_P) csr_p[p4.y * CAP_P + a] = s4.y;
    }
    if ((u32)(p4.z - p_lo) < (u32)pch) {
      int a = atomicAdd(&cnt_p[p4.z], 1);
      if (a < CAP_P) csr_p[p4.z * CAP_P + a] = s4.z;
    }
    if ((u32)(p4.w - p_lo) < (u32)pch) {
      int a = atomicAdd(&cnt_p[p4.w], 1);
      if (a < CAP_P) csr_p[p4.w * CAP_P + a] = s4.w;
    }
    if ((u32)(s4.x - s_lo) < (u32)sch) {
      int a = atomicAdd(&cnt_s[s4.x], 1);
      if (a < CAP_S) csr_s[s4.x * CAP_S + a] = p4.x;
    }
    if ((u32)(s4.y - s_lo) < (u32)sch) {
      int a = atomicAdd(&cnt_s[s4.y], 1);
      if (a < CAP_S) csr_s[s4.y * CAP_S + a] = p4.y;
    }
    if ((u32)(s4.z - s_lo) < (u32)sch) {
      int a = atomicAdd(&cnt_s[s4.z], 1);
      if (a < CAP_S) csr_s[s4.z * CAP_S + a] = p4.z;
    }
    if ((u32)(s4.w - s_lo) < (u32)sch) {
      int a = atomicAdd(&cnt_s[s4.w], 1);
      if (a < CAP_S) csr_s[s4.w * CAP_S + a] = p4.w;
    }
  }
  if (g == 0 && threadIdx.x == 0) {
    for (int i = e4 << 2; i < e; i++) {
      int p = ep[i], s = es[i];
      if ((u32)(p - p_lo) < (u32)pch) {
        int a = atomicAdd(&cnt_p[p], 1);
        if (a < CAP_P) csr_p[p * CAP_P + a] = s;
      }
      if ((u32)(s - s_lo) < (u32)sch) {
        int a = atomicAdd(&cnt_s[s], 1);
        if (a < CAP_S) csr_s[s * CAP_S + a] = p;
      }
    }
  }
}

// ---- quad-group PURE mean aggregation, fixed-stride CSR --------------------
__global__ __launch_bounds__(256) void agg_mean_k(
    const u16* __restrict__ feat, const int* __restrict__ csr, int cap,
    const int* __restrict__ cnt, u16* __restrict__ out, int n)
{
  int lr = threadIdx.x & 15;
  int grp = threadIdx.x >> 4;           // 0..15
  int gv = blockIdx.x * 16 + grp;
  if (gv >= n) return;
  int b = gv * cap;
  int c = cnt[gv];
  int cm = min(c, cap);
  float s0=0,s1=0,s2=0,s3=0,s4=0,s5=0,s6=0,s7=0;
  for (int i = 0; i < cm; i += 8) {
    int m = cm - i;
    int idx[8];
#pragma unroll
    for (int u = 0; u < 8; u++) idx[u] = csr[b + i + min(u, m - 1)];
#pragma unroll
    for (int u = 0; u < 8; u++) {
      uint4 v = ((const uint4*)(feat + (size_t)idx[u] * 128))[lr];
      if (u < m) {
        s0 += bf_lo(v.x); s1 += bf_hi(v.x);
        s2 += bf_lo(v.y); s3 += bf_hi(v.y);
        s4 += bf_lo(v.z); s5 += bf_hi(v.z);
        s6 += bf_lo(v.w); s7 += bf_hi(v.w);
      }
    }
  }
  float inv = (c > 0) ? 1.0f / (float)c : 0.0f;
  uint4 o;
  o.x = pack2(s0 * inv, s1 * inv);
  o.y = pack2(s2 * inv, s3 * inv);
  o.z = pack2(s4 * inv, s5 * inv);
  o.w = pack2(s6 * inv, s7 * inv);
  ((uint4*)(out + (size_t)gv * 128))[lr] = o;
}

// ---- K=256 fused GEMM, LDS-staged B ----------------------------------------
// C[M,128] = act( A1@W1 + A2@W2 + bias ). Both W matrices staged to LDS
// once per block (64KB, 2 blocks/CU); B-frags via ds_read_b128 with
// XOR-swizzle chunk^=(row&7) (16B units) on store+read (bank-conflict-free
// per G4: identical geometry to the verified attn K_lds case).
__global__ __launch_bounds__(256) void gemm2_lds_k(
    const u16* __restrict__ A1, const u16* __restrict__ W1,
    const u16* __restrict__ A2, const u16* __restrict__ W2,
    const float* __restrict__ bias,
    void* __restrict__ Cout, int M, int doRelu, int outF32)
{
  __shared__ uint4 ldsW[2][2048];   // 2 x 32KB, [row(128)][chunk16(16)]
  int tid = threadIdx.x;
  for (int i = tid; i < 2048; i += 256) {
    int row = i >> 4, ch = i & 15;
    int ph = (row << 4) | (ch ^ (row & 7));
    ldsW[0][ph] = ((const uint4*)W1)[i];
    ldsW[1][ph] = ((const uint4*)W2)[i];
  }
  __syncthreads();

  int lane = tid & 63;
  int r = lane & 15, q = lane >> 4;
  int wid = (blockIdx.x * 256 + tid) >> 6;
  int nw = gridDim.x * 4;
  const u16* As[2] = {A1, A2};

  for (int strip = wid; strip * 16 < M; strip += nw) {
    ffrag acc[8];
#pragma unroll
    for (int j = 0; j < 8; j++) acc[j] = (ffrag)0.f;

#pragma unroll 1
    for (int h = 0; h < 2; h++) {
      const u16* arow = As[h] + (size_t)(strip * 16 + r) * 128 + q * 8;
      bfrag a[4];
      a[0] = *(const bfrag*)(arow);
      a[1] = *(const bfrag*)(arow + 32);
      a[2] = *(const bfrag*)(arow + 64);
      a[3] = *(const bfrag*)(arow + 96);
#pragma unroll
      for (int k0 = 0; k0 < 4; k0++) {
        // chunk = k0*4+q, row = j*16+r -> row&7 == r&7 (j-invariant)
        int base = (r << 4) | (((k0 << 2) | q) ^ (r & 7));
#pragma unroll
        for (int j = 0; j < 8; j++) {
          const bfrag* bp = (const bfrag*)&ldsW[h][(j << 8) | base];
          acc[j] = __builtin_amdgcn_mfma_f32_16x16x32_bf16(*bp, a[k0], acc[j], 0, 0, 0);
        }
      }
    }

    size_t row = (size_t)(strip * 16 + r);
#pragma unroll
    for (int j = 0; j < 8; j++) {
      int col0 = j * 16 + q * 4;
      float v0 = acc[j][0], v1 = acc[j][1], v2 = acc[j][2], v3 = acc[j][3];
      if (bias) {
        float4 bv = *(const float4*)(bias + col0);
        v0 += bv.x; v1 += bv.y; v2 += bv.z; v3 += bv.w;
      }
      if (doRelu) {
        v0 = fmaxf(v0, 0.f); v1 = fmaxf(v1, 0.f);
        v2 = fmaxf(v2, 0.f); v3 = fmaxf(v3, 0.f);
      }
      if (outF32) {
        *(float4*)((float*)Cout + row * 128 + col0) = make_float4(v0, v1, v2, v3);
      } else {
        ushort4 o;
        o.x = f2bf(v0); o.y = f2bf(v1); o.z = f2bf(v2); o.w = f2bf(v3);
        *(ushort4*)((u16*)Cout + row * 128 + col0) = o;
      }
    }
  }
}

// ---------------------------------------------------------------------------

extern "C" void kernel_launch(void* const* d_in, const int* in_sizes, int n_in,
                              void* d_out, int out_size, void* d_ws, size_t ws_size,
                              hipStream_t stream)
{
  const float* song_x = (const float*)d_in[0];
  const int*   pid    = (const int*)d_in[1];
  const int*   e_song = (const int*)d_in[2];
  const int*   e_play = (const int*)d_in[3];
  const float* emb    = (const float*)d_in[4];
  const float* Wl1_sp = (const float*)d_in[5];
  const float* Wr1_sp = (const float*)d_in[6];
  const float* b1_sp  = (const float*)d_in[7];
  const float* Wl1_ps = (const float*)d_in[8];
  const float* Wr1_ps = (const float*)d_in[9];
  const float* b1_ps  = (const float*)d_in[10];
  const float* Wl2_sp = (const float*)d_in[11];
  const float* Wr2_sp = (const float*)d_in[12];
  const float* b2_sp  = (const float*)d_in[13];
  const float* Wl2_ps = (const float*)d_in[14];
  const float* Wr2_ps = (const float*)d_in[15];
  const float* b2_ps  = (const float*)d_in[16];

  const int NS = in_sizes[0] / 128;
  const int NP = in_sizes[1];
  const int E  = in_sizes[2];

  char* w = (char*)d_ws;
  auto alloc = [&](size_t bytes) { char* p = w; w += ws_align(bytes); return p; };
  u16* x_play = (u16*)alloc((size_t)NP * 128 * 2);
  u16* Ms     = (u16*)alloc((size_t)NP * 128 * 2);   // mean_p(...)  [NP,128]
  u16* p1     = (u16*)alloc((size_t)NP * 128 * 2);
  u16* s1     = (u16*)alloc((size_t)NS * 128 * 2);
  u16* xs     = (u16*)alloc((size_t)NS * 128 * 2);
  u16* Msong  = (u16*)alloc((size_t)NS * 128 * 2);   // mean_s(...)  [NS,128]
  u16* Wt     = (u16*)alloc((size_t)8 * 16384 * 2);  // [mat][n][k]
  int* cnt_p  = (int*)alloc(((size_t)NP + NS) * 4);
  int* cnt_s  = cnt_p + NP;
  int* csr_p  = (int*)alloc((size_t)NP * CAP_P * 4);
  int* csr_s  = (int*)alloc((size_t)NS * CAP_S * 4);

  float* s2_out = (float*)d_out;
  float* p2_out = (float*)d_out + (size_t)NS * 128;

  u16* Wt_l1sp = Wt + 0 * 16384;
  u16* Wt_r1sp = Wt + 1 * 16384;
  u16* Wt_l1ps = Wt + 2 * 16384;
  u16* Wt_r1ps = Wt + 3 * 16384;
  u16* Wt_l2sp = Wt + 4 * 16384;
  u16* Wt_r2sp = Wt + 5 * 16384;
  u16* Wt_l2ps = Wt + 6 * 16384;
  u16* Wt_r2ps = Wt + 7 * 16384;

  // LDS-gemm2 grids: enough blocks for 2/CU residency; strip-stride loop.
  const int g2S = 512;
  const int g2P = 313;   // ceil(1250 strips / 4 waves)
  const int aggP_b = (NP + 15) / 16, aggS_b = (NS + 15) / 16;
  const int pch = (NP + 7) / 8, sch = (NS + 7) / 8;

  // ---- prep (also zeros degree counters) ----
  prep_k<<<1024, 256, 0, stream>>>(Wl1_sp, Wr1_sp, Wl1_ps, Wr1_ps,
                                   Wl2_sp, Wr2_sp, Wl2_ps, Wr2_ps, Wt,
                                   song_x, xs, NS * 32,
                                   emb, pid, x_play, NP,
                                   cnt_p, NP + NS);

  // ---- CSR build (XCD-chunked atomic wall; standalone) ----
  build_k<<<1024, 256, 0, stream>>>(e_song, e_play, cnt_s, cnt_p,
                                    csr_s, csr_p, E, pch, sch);

  // ---- layer 1 ----
  // Msong1 = mean_s(x_play)   (gather source 5MB, L2-resident)
  agg_mean_k<<<aggS_b, 256, 0, stream>>>(x_play, csr_s, CAP_S, cnt_s,
                                         Msong, NS);
  // Ms1 = mean_p(xs)
  agg_mean_k<<<aggP_b, 256, 0, stream>>>(xs, csr_p, CAP_P, cnt_p,
                                         Ms, NP);
  // s1 = relu(Msong1@Wl1_ps + xs@Wr1_ps + b1_ps)   [K=256, LDS-B]
  gemm2_lds_k<<<g2S, 256, 0, stream>>>(Msong, Wt_l1ps, xs, Wt_r1ps,
                                       b1_ps, s1, NS, 1, 0);
  // p1 = relu(Ms1@Wl1_sp + x_play@Wr1_sp + b1_sp)  [K=256, LDS-B]
  gemm2_lds_k<<<g2P, 256, 0, stream>>>(Ms, Wt_l1sp, x_play, Wt_r1sp,
                                       b1_sp, p1, NP, 1, 0);

  // ---- layer 2 ----
  // Msong2 = mean_s(p1)
  agg_mean_k<<<aggS_b, 256, 0, stream>>>(p1, csr_s, CAP_S, cnt_s,
                                         Msong, NS);
  // Ms2 = mean_p(s1)
  agg_mean_k<<<aggP_b, 256, 0, stream>>>(s1, csr_p, CAP_P, cnt_p,
                                         Ms, NP);
  // s2 = Msong2@Wl2_ps + s1@Wr2_ps + b2_ps  (f32 out)
  gemm2_lds_k<<<g2S, 256, 0, stream>>>(Msong, Wt_l2ps, s1, Wt_r2ps,
                                       b2_ps, s2_out, NS, 0, 1);
  // p2 = Ms2@Wl2_sp + p1@Wr2_sp + b2_sp  (f32 out)
  gemm2_lds_k<<<g2P, 256, 0, stream>>>(Ms, Wt_l2sp, p1, Wt_r2sp,
                                       b2_sp, p2_out, NP, 0, 1);
}

// Round 13
// 329.957 us; speedup vs baseline: 1.4652x; 1.0754x over previous
//
#include <hip/hip_runtime.h>

// ---------------------------------------------------------------------------
// 2-layer hetero GraphSAGE, bf16-MFMA.
// R19: R18 with compile fix (gemm2_pair_k call sites were missing the
//      final nb2 arg). Same-kernel pairing:
//      - 2 aggs per layer merged into one dispatch (block-range split);
//        2 gemm2s per layer merged likewise. Both branches inline the
//        SAME device body -> no VGPR homogenization (R12 trap avoided).
//      - 6 dispatches: prep, build, aggpair1, gemmpair1, aggpair2,
//        gemmpair2.
//      - Base R17 (354us): mean/linear commutation, K=256 gemm2 with
//        LDS-staged+XOR-swizzled B, XCD-chunked fixed-cap CSR build
//        (~50us atomic-rate floor), quad-group pure-mean agg.
// ---------------------------------------------------------------------------

typedef __attribute__((ext_vector_type(8))) short bfrag;   // 8 bf16 (4 VGPRs)
typedef __attribute__((ext_vector_type(4))) float ffrag;   // 4 fp32 acc
typedef unsigned short u16;
typedef unsigned int u32;

#define CAP_P 64   // max playlist degree guard (Binomial mean 25, max ~47)
#define CAP_S 32   // max song degree guard (Binomial mean 5, max ~20)

static inline size_t ws_align(size_t x) { return (x + 255) & ~size_t(255); }

__device__ inline u16 f2bf(float f) {
  union { float f; u32 u; } v; v.f = f;
  u32 r = v.u + 0x7fffu + ((v.u >> 16) & 1u);   // round-nearest-even
  return (u16)(r >> 16);
}
__device__ inline u32 pack2(float a, float b) {
  return (u32)f2bf(a) | ((u32)f2bf(b) << 16);
}
__device__ inline float bf_lo(u32 p) {
  union { u32 u; float f; } v; v.u = p << 16; return v.f;
}
__device__ inline float bf_hi(u32 p) {
  union { u32 u; float f; } v; v.u = p & 0xffff0000u; return v.f;
}

// ---- prep: zero counters, weight transpose+cast, song cast, playlist gather
__global__ __launch_bounds__(256) void prep_k(
    const float* __restrict__ w0, const float* __restrict__ w1,
    const float* __restrict__ w2, const float* __restrict__ w3,
    const float* __restrict__ w4, const float* __restrict__ w5,
    const float* __restrict__ w6, const float* __restrict__ w7,
    u16* __restrict__ Wt,
    const float* __restrict__ song_x, u16* __restrict__ xs, int ns4,
    const float* __restrict__ emb, const int* __restrict__ pid,
    u16* __restrict__ xp, int np,
    int* __restrict__ zero_region, int nzero)
{
  int g0 = blockIdx.x * 256 + threadIdx.x;
  int gs = gridDim.x * 256;
  for (int i = g0; i < nzero; i += gs) zero_region[i] = 0;
  const float* ws[8] = {w0, w1, w2, w3, w4, w5, w6, w7};
  for (int idx = g0; idx < 8 * 16384; idx += gs) {
    int m = idx >> 14, rem = idx & 16383;
    int n = rem >> 7, k = rem & 127;
    Wt[idx] = f2bf(ws[m][k * 128 + n]);
  }
  for (int i = g0; i < ns4; i += gs) {
    float4 v = ((const float4*)song_x)[i];
    ushort4 o;
    o.x = f2bf(v.x); o.y = f2bf(v.y); o.z = f2bf(v.z); o.w = f2bf(v.w);
    ((ushort4*)xs)[i] = o;
  }
  for (int i = g0; i < np * 32; i += gs) {
    int node = i >> 5, q = i & 31;
    float4 v = ((const float4*)(emb + (size_t)pid[node] * 128))[q];
    ushort4 o;
    o.x = f2bf(v.x); o.y = f2bf(v.y); o.z = f2bf(v.z); o.w = f2bf(v.w);
    ((ushort4*)(xp + (size_t)node * 128))[q] = o;
  }
}

// ---- fixed-capacity CSR build, XCD-chunked ---------------------------------
__global__ __launch_bounds__(256) void build_k(
    const int* __restrict__ es, const int* __restrict__ ep,
    int* __restrict__ cnt_s, int* __restrict__ cnt_p,
    int* __restrict__ csr_s, int* __restrict__ csr_p,
    int e, int pch, int sch)
{
  int j = blockIdx.x & 7;
  int g = blockIdx.x >> 3;
  int nb = gridDim.x >> 3;
  int p_lo = j * pch, s_lo = j * sch;
  int e4 = e >> 2;
  int gs = nb * 256;
  for (int i = g * 256 + threadIdx.x; i < e4; i += gs) {
    int4 p4 = ((const int4*)ep)[i];
    int4 s4 = ((const int4*)es)[i];
    if ((u32)(p4.x - p_lo) < (u32)pch) {
      int a = atomicAdd(&cnt_p[p4.x], 1);
      if (a < CAP_P) csr_p[p4.x * CAP_P + a] = s4.x;
    }
    if ((u32)(p4.y - p_lo) < (u32)pch) {
      int a = atomicAdd(&cnt_p[p4.y], 1);
      if (a < CAP_P) csr_p[p4.y * CAP_P + a] = s4.y;
    }
    if ((u32)(p4.z - p_lo) < (u32)pch) {
      int a = atomicAdd(&cnt_p[p4.z], 1);
      if (a < CAP_P) csr_p[p4.z * CAP_P + a] = s4.z;
    }
    if ((u32)(p4.w - p_lo) < (u32)pch) {
      int a = atomicAdd(&cnt_p[p4.w], 1);
      if (a < CAP_P) csr_p[p4.w * CAP_P + a] = s4.w;
    }
    if ((u32)(s4.x - s_lo) < (u32)sch) {
      int a = atomicAdd(&cnt_s[s4.x], 1);
      if (a < CAP_S) csr_s[s4.x * CAP_S + a] = p4.x;
    }
    if ((u32)(s4.y - s_lo) < (u32)sch) {
      int a = atomicAdd(&cnt_s[s4.y], 1);
      if (a < CAP_S) csr_s[s4.y * CAP_S + a] = p4.y;
    }
    if ((u32)(s4.z - s_lo) < (u32)sch) {
      int a = atomicAdd(&cnt_s[s4.z], 1);
      if (a < CAP_S) csr_s[s4.z * CAP_S + a] = p4.z;
    }
    if ((u32)(s4.w - s_lo) < (u32)sch) {
      int a = atomicAdd(&cnt_s[s4.w], 1);
      if (a < CAP_S) csr_s[s4.w * CAP_S + a] = p4.w;
    }
  }
  if (g == 0 && threadIdx.x == 0) {
    for (int i = e4 << 2; i < e; i++) {
      int p = ep[i], s = es[i];
      if ((u32)(p - p_lo) < (u32)pch) {
        int a = atomicAdd(&cnt_p[p], 1);
        if (a < CAP_P) csr_p[p * CAP_P + a] = s;
      }
      if ((u32)(s - s_lo) < (u32)sch) {
        int a = atomicAdd(&cnt_s[s], 1);
        if (a < CAP_S) csr_s[s * CAP_S + a] = p;
      }
    }
  }
}

// ---- quad-group PURE mean aggregation (device body) ------------------------
__device__ inline void d_agg_mean(int bid,
    const u16* feat, const int* csr, int cap, const int* cnt,
    u16* out, int n)
{
  int lr = threadIdx.x & 15;
  int grp = threadIdx.x >> 4;           // 0..15
  int gv = bid * 16 + grp;
  if (gv >= n) return;
  int b = gv * cap;
  int c = cnt[gv];
  int cm = min(c, cap);
  float s0=0,s1=0,s2=0,s3=0,s4=0,s5=0,s6=0,s7=0;
  for (int i = 0; i < cm; i += 8) {
    int m = cm - i;
    int idx[8];
#pragma unroll
    for (int u = 0; u < 8; u++) idx[u] = csr[b + i + min(u, m - 1)];
#pragma unroll
    for (int u = 0; u < 8; u++) {
      uint4 v = ((const uint4*)(feat + (size_t)idx[u] * 128))[lr];
      if (u < m) {
        s0 += bf_lo(v.x); s1 += bf_hi(v.x);
        s2 += bf_lo(v.y); s3 += bf_hi(v.y);
        s4 += bf_lo(v.z); s5 += bf_hi(v.z);
        s6 += bf_lo(v.w); s7 += bf_hi(v.w);
      }
    }
  }
  float inv = (c > 0) ? 1.0f / (float)c : 0.0f;
  uint4 o;
  o.x = pack2(s0 * inv, s1 * inv);
  o.y = pack2(s2 * inv, s3 * inv);
  o.z = pack2(s4 * inv, s5 * inv);
  o.w = pack2(s6 * inv, s7 * inv);
  ((uint4*)(out + (size_t)gv * 128))[lr] = o;
}

// ---- paired agg dispatch: problem1 blocks [0,nb1), problem2 after ----------
__global__ __launch_bounds__(256) void agg_pair_k(
    const u16* f1, const int* c1, int cap1, const int* n1v, u16* o1, int n1,
    int nb1,
    const u16* f2, const int* c2, int cap2, const int* n2v, u16* o2, int n2)
{
  int b = blockIdx.x;
  if (b < nb1) d_agg_mean(b, f1, c1, cap1, n1v, o1, n1);
  else         d_agg_mean(b - nb1, f2, c2, cap2, n2v, o2, n2);
}

// ---- K=256 fused GEMM, LDS-staged B (device body) --------------------------
// ldsW: 4096 uint4 (64KB): [h(2)][row(128)][chunk16(16)], chunk^=(row&7).
__device__ inline void d_gemm2_lds(uint4* ldsW, int bid, int nb,
    const u16* A1, const u16* W1, const u16* A2, const u16* W2,
    const float* bias, void* Cout, int M, int doRelu, int outF32)
{
  int tid = threadIdx.x;
  for (int i = tid; i < 2048; i += 256) {
    int row = i >> 4, ch = i & 15;
    int ph = (row << 4) | (ch ^ (row & 7));
    ldsW[ph] = ((const uint4*)W1)[i];
    ldsW[2048 + ph] = ((const uint4*)W2)[i];
  }
  __syncthreads();

  int lane = tid & 63;
  int r = lane & 15, q = lane >> 4;
  int wid = (bid * 256 + tid) >> 6;
  int nw = nb * 4;
  const u16* As[2] = {A1, A2};

  for (int strip = wid; strip * 16 < M; strip += nw) {
    ffrag acc[8];
#pragma unroll
    for (int j = 0; j < 8; j++) acc[j] = (ffrag)0.f;

#pragma unroll 1
    for (int h = 0; h < 2; h++) {
      const u16* arow = As[h] + (size_t)(strip * 16 + r) * 128 + q * 8;
      bfrag a[4];
      a[0] = *(const bfrag*)(arow);
      a[1] = *(const bfrag*)(arow + 32);
      a[2] = *(const bfrag*)(arow + 64);
      a[3] = *(const bfrag*)(arow + 96);
      const uint4* lw = ldsW + (h << 11);
#pragma unroll
      for (int k0 = 0; k0 < 4; k0++) {
        // chunk = k0*4+q, row = j*16+r -> row&7 == r&7 (j-invariant)
        int base = (r << 4) | (((k0 << 2) | q) ^ (r & 7));
#pragma unroll
        for (int j = 0; j < 8; j++) {
          const bfrag* bp = (const bfrag*)&lw[(j << 8) | base];
          acc[j] = __builtin_amdgcn_mfma_f32_16x16x32_bf16(*bp, a[k0], acc[j], 0, 0, 0);
        }
      }
    }

    size_t row = (size_t)(strip * 16 + r);
#pragma unroll
    for (int j = 0; j < 8; j++) {
      int col0 = j * 16 + q * 4;
      float v0 = acc[j][0], v1 = acc[j][1], v2 = acc[j][2], v3 = acc[j][3];
      if (bias) {
        float4 bv = *(const float4*)(bias + col0);
        v0 += bv.x; v1 += bv.y; v2 += bv.z; v3 += bv.w;
      }
      if (doRelu) {
        v0 = fmaxf(v0, 0.f); v1 = fmaxf(v1, 0.f);
        v2 = fmaxf(v2, 0.f); v3 = fmaxf(v3, 0.f);
      }
      if (outF32) {
        *(float4*)((float*)Cout + row * 128 + col0) = make_float4(v0, v1, v2, v3);
      } else {
        ushort4 o;
        o.x = f2bf(v0); o.y = f2bf(v1); o.z = f2bf(v2); o.w = f2bf(v3);
        *(ushort4*)((u16*)Cout + row * 128 + col0) = o;
      }
    }
  }
}

// ---- paired gemm2 dispatch: problem1 blocks [0,nb1), problem2 after --------
// Both branches inline the SAME body -> identical VGPR alloc; one 64KB LDS.
__global__ __launch_bounds__(256) void gemm2_pair_k(
    const u16* A1a, const u16* W1a, const u16* A2a, const u16* W2a,
    const float* ba, void* Ca, int Ma, int ra, int oa, int nb1,
    const u16* A1b, const u16* W1b, const u16* A2b, const u16* W2b,
    const float* bb, void* Cb, int Mb, int rb, int ob, int nb2)
{
  __shared__ uint4 ldsW[4096];   // 64KB
  int b = blockIdx.x;
  if (b < nb1)
    d_gemm2_lds(ldsW, b, nb1, A1a, W1a, A2a, W2a, ba, Ca, Ma, ra, oa);
  else
    d_gemm2_lds(ldsW, b - nb1, nb2, A1b, W1b, A2b, W2b, bb, Cb, Mb, rb, ob);
}

// ---------------------------------------------------------------------------

extern "C" void kernel_launch(void* const* d_in, const int* in_sizes, int n_in,
                              void* d_out, int out_size, void* d_ws, size_t ws_size,
                              hipStream_t stream)
{
  const float* song_x = (const float*)d_in[0];
  const int*   pid    = (const int*)d_in[1];
  const int*   e_song = (const int*)d_in[2];
  const int*   e_play = (const int*)d_in[3];
  const float* emb    = (const float*)d_in[4];
  const float* Wl1_sp = (const float*)d_in[5];
  const float* Wr1_sp = (const float*)d_in[6];
  const float* b1_sp  = (const float*)d_in[7];
  const float* Wl1_ps = (const float*)d_in[8];
  const float* Wr1_ps = (const float*)d_in[9];
  const float* b1_ps  = (const float*)d_in[10];
  const float* Wl2_sp = (const float*)d_in[11];
  const float* Wr2_sp = (const float*)d_in[12];
  const float* b2_sp  = (const float*)d_in[13];
  const float* Wl2_ps = (const float*)d_in[14];
  const float* Wr2_ps = (const float*)d_in[15];
  const float* b2_ps  = (const float*)d_in[16];

  const int NS = in_sizes[0] / 128;
  const int NP = in_sizes[1];
  const int E  = in_sizes[2];

  char* w = (char*)d_ws;
  auto alloc = [&](size_t bytes) { char* p = w; w += ws_align(bytes); return p; };
  u16* x_play = (u16*)alloc((size_t)NP * 128 * 2);
  u16* Ms     = (u16*)alloc((size_t)NP * 128 * 2);   // mean_p(...)  [NP,128]
  u16* p1     = (u16*)alloc((size_t)NP * 128 * 2);
  u16* s1     = (u16*)alloc((size_t)NS * 128 * 2);
  u16* xs     = (u16*)alloc((size_t)NS * 128 * 2);
  u16* Msong  = (u16*)alloc((size_t)NS * 128 * 2);   // mean_s(...)  [NS,128]
  u16* Wt     = (u16*)alloc((size_t)8 * 16384 * 2);  // [mat][n][k]
  int* cnt_p  = (int*)alloc(((size_t)NP + NS) * 4);
  int* cnt_s  = cnt_p + NP;
  int* csr_p  = (int*)alloc((size_t)NP * CAP_P * 4);
  int* csr_s  = (int*)alloc((size_t)NS * CAP_S * 4);

  float* s2_out = (float*)d_out;
  float* p2_out = (float*)d_out + (size_t)NS * 128;

  u16* Wt_l1sp = Wt + 0 * 16384;
  u16* Wt_r1sp = Wt + 1 * 16384;
  u16* Wt_l1ps = Wt + 2 * 16384;
  u16* Wt_r1ps = Wt + 3 * 16384;
  u16* Wt_l2sp = Wt + 4 * 16384;
  u16* Wt_r2sp = Wt + 5 * 16384;
  u16* Wt_l2ps = Wt + 6 * 16384;
  u16* Wt_r2ps = Wt + 7 * 16384;

  const int g2S = 512;   // 64KB LDS -> 2 blocks/CU -> 512 fills the chip
  const int g2P = 313;   // ceil(1250 strips / 4 waves)
  const int aggP_b = (NP + 15) / 16, aggS_b = (NS + 15) / 16;
  const int pch = (NP + 7) / 8, sch = (NS + 7) / 8;

  // ---- prep (also zeros degree counters) ----
  prep_k<<<1024, 256, 0, stream>>>(Wl1_sp, Wr1_sp, Wl1_ps, Wr1_ps,
                                   Wl2_sp, Wr2_sp, Wl2_ps, Wr2_ps, Wt,
                                   song_x, xs, NS * 32,
                                   emb, pid, x_play, NP,
                                   cnt_p, NP + NS);

  // ---- CSR build (XCD-chunked atomic wall; standalone) ----
  build_k<<<1024, 256, 0, stream>>>(e_song, e_play, cnt_s, cnt_p,
                                    csr_s, csr_p, E, pch, sch);

  // ---- layer 1: Ms1 = mean_p(xs) || Msong1 = mean_s(x_play) ----
  agg_pair_k<<<aggP_b + aggS_b, 256, 0, stream>>>(
      xs, csr_p, CAP_P, cnt_p, Ms, NP, aggP_b,
      x_play, csr_s, CAP_S, cnt_s, Msong, NS);

  // ---- layer 1: s1 = relu(Msong@Wl1_ps + xs@Wr1_ps + b1_ps)
  //            || p1 = relu(Ms@Wl1_sp + x_play@Wr1_sp + b1_sp) ----
  gemm2_pair_k<<<g2S + g2P, 256, 0, stream>>>(
      Msong, Wt_l1ps, xs, Wt_r1ps, b1_ps, (void*)s1, NS, 1, 0, g2S,
      Ms, Wt_l1sp, x_play, Wt_r1sp, b1_sp, (void*)p1, NP, 1, 0, g2P);

  // ---- layer 2: Ms2 = mean_p(s1) || Msong2 = mean_s(p1) ----
  agg_pair_k<<<aggP_b + aggS_b, 256, 0, stream>>>(
      s1, csr_p, CAP_P, cnt_p, Ms, NP, aggP_b,
      p1, csr_s, CAP_S, cnt_s, Msong, NS);

  // ---- layer 2: s2 = Msong@Wl2_ps + s1@Wr2_ps + b2_ps  (f32)
  //            || p2 = Ms@Wl2_sp + p1@Wr2_sp + b2_sp  (f32) ----
  gemm2_pair_k<<<g2S + g2P, 256, 0, stream>>>(
      Msong, Wt_l2ps, s1, Wt_r2ps, b2_ps, (void*)s2_out, NS, 0, 1, g2S,
      Ms, Wt_l2sp, p1, Wt_r2sp, b2_sp, (void*)p2_out, NP, 0, 1, g2P);
}

// Round 14
// 319.754 us; speedup vs baseline: 1.5119x; 1.0319x over previous
//
#include <hip/hip_runtime.h>

// ---------------------------------------------------------------------------
// 2-layer hetero GraphSAGE, bf16-MFMA.
// R20: - R19 base (330us): same-kernel pairing (aggpair/gemmpair), K=256
//        gemm2 with LDS-staged+XOR-swizzled B, mean/linear commutation,
//        XCD-chunked fixed-cap CSR build (~49us atomic-rate floor, 5x
//        measured - exhausted), quad-group pure-mean agg. 6 dispatches.
//      - NEW: gemm2_pair_k at 512 threads/block. 64KB LDS + 256 threads
//        was 2 blocks/CU = 8 waves/CU (25% occ) - not enough TLP to hide
//        the per-strip A-loads from L2. 512 threads: same 2 blocks/CU,
//        16 waves/CU (the ~76-VGPR limit), 2x latency hiding, half the
//        W-staging block count. Inner loop untouched.
// ---------------------------------------------------------------------------

typedef __attribute__((ext_vector_type(8))) short bfrag;   // 8 bf16 (4 VGPRs)
typedef __attribute__((ext_vector_type(4))) float ffrag;   // 4 fp32 acc
typedef unsigned short u16;
typedef unsigned int u32;

#define CAP_P 64   // max playlist degree guard (Binomial mean 25, max ~47)
#define CAP_S 32   // max song degree guard (Binomial mean 5, max ~20)

static inline size_t ws_align(size_t x) { return (x + 255) & ~size_t(255); }

__device__ inline u16 f2bf(float f) {
  union { float f; u32 u; } v; v.f = f;
  u32 r = v.u + 0x7fffu + ((v.u >> 16) & 1u);   // round-nearest-even
  return (u16)(r >> 16);
}
__device__ inline u32 pack2(float a, float b) {
  return (u32)f2bf(a) | ((u32)f2bf(b) << 16);
}
__device__ inline float bf_lo(u32 p) {
  union { u32 u; float f; } v; v.u = p << 16; return v.f;
}
__device__ inline float bf_hi(u32 p) {
  union { u32 u; float f; } v; v.u = p & 0xffff0000u; return v.f;
}

// ---- prep: zero counters, weight transpose+cast, song cast, playlist gather
__global__ __launch_bounds__(256) void prep_k(
    const float* __restrict__ w0, const float* __restrict__ w1,
    const float* __restrict__ w2, const float* __restrict__ w3,
    const float* __restrict__ w4, const float* __restrict__ w5,
    const float* __restrict__ w6, const float* __restrict__ w7,
    u16* __restrict__ Wt,
    const float* __restrict__ song_x, u16* __restrict__ xs, int ns4,
    const float* __restrict__ emb, const int* __restrict__ pid,
    u16* __restrict__ xp, int np,
    int* __restrict__ zero_region, int nzero)
{
  int g0 = blockIdx.x * 256 + threadIdx.x;
  int gs = gridDim.x * 256;
  for (int i = g0; i < nzero; i += gs) zero_region[i] = 0;
  const float* ws[8] = {w0, w1, w2, w3, w4, w5, w6, w7};
  for (int idx = g0; idx < 8 * 16384; idx += gs) {
    int m = idx >> 14, rem = idx & 16383;
    int n = rem >> 7, k = rem & 127;
    Wt[idx] = f2bf(ws[m][k * 128 + n]);
  }
  for (int i = g0; i < ns4; i += gs) {
    float4 v = ((const float4*)song_x)[i];
    ushort4 o;
    o.x = f2bf(v.x); o.y = f2bf(v.y); o.z = f2bf(v.z); o.w = f2bf(v.w);
    ((ushort4*)xs)[i] = o;
  }
  for (int i = g0; i < np * 32; i += gs) {
    int node = i >> 5, q = i & 31;
    float4 v = ((const float4*)(emb + (size_t)pid[node] * 128))[q];
    ushort4 o;
    o.x = f2bf(v.x); o.y = f2bf(v.y); o.z = f2bf(v.z); o.w = f2bf(v.w);
    ((ushort4*)(xp + (size_t)node * 128))[q] = o;
  }
}

// ---- fixed-capacity CSR build, XCD-chunked ---------------------------------
__global__ __launch_bounds__(256) void build_k(
    const int* __restrict__ es, const int* __restrict__ ep,
    int* __restrict__ cnt_s, int* __restrict__ cnt_p,
    int* __restrict__ csr_s, int* __restrict__ csr_p,
    int e, int pch, int sch)
{
  int j = blockIdx.x & 7;
  int g = blockIdx.x >> 3;
  int nb = gridDim.x >> 3;
  int p_lo = j * pch, s_lo = j * sch;
  int e4 = e >> 2;
  int gs = nb * 256;
  for (int i = g * 256 + threadIdx.x; i < e4; i += gs) {
    int4 p4 = ((const int4*)ep)[i];
    int4 s4 = ((const int4*)es)[i];
    if ((u32)(p4.x - p_lo) < (u32)pch) {
      int a = atomicAdd(&cnt_p[p4.x], 1);
      if (a < CAP_P) csr_p[p4.x * CAP_P + a] = s4.x;
    }
    if ((u32)(p4.y - p_lo) < (u32)pch) {
      int a = atomicAdd(&cnt_p[p4.y], 1);
      if (a < CAP_P) csr_p[p4.y * CAP_P + a] = s4.y;
    }
    if ((u32)(p4.z - p_lo) < (u32)pch) {
      int a = atomicAdd(&cnt_p[p4.z], 1);
      if (a < CAP_P) csr_p[p4.z * CAP_P + a] = s4.z;
    }
    if ((u32)(p4.w - p_lo) < (u32)pch) {
      int a = atomicAdd(&cnt_p[p4.w], 1);
      if (a < CAP_P) csr_p[p4.w * CAP_P + a] = s4.w;
    }
    if ((u32)(s4.x - s_lo) < (u32)sch) {
      int a = atomicAdd(&cnt_s[s4.x], 1);
      if (a < CAP_S) csr_s[s4.x * CAP_S + a] = p4.x;
    }
    if ((u32)(s4.y - s_lo) < (u32)sch) {
      int a = atomicAdd(&cnt_s[s4.y], 1);
      if (a < CAP_S) csr_s[s4.y * CAP_S + a] = p4.y;
    }
    if ((u32)(s4.z - s_lo) < (u32)sch) {
      int a = atomicAdd(&cnt_s[s4.z], 1);
      if (a < CAP_S) csr_s[s4.z * CAP_S + a] = p4.z;
    }
    if ((u32)(s4.w - s_lo) < (u32)sch) {
      int a = atomicAdd(&cnt_s[s4.w], 1);
      if (a < CAP_S) csr_s[s4.w * CAP_S + a] = p4.w;
    }
  }
  if (g == 0 && threadIdx.x == 0) {
    for (int i = e4 << 2; i < e; i++) {
      int p = ep[i], s = es[i];
      if ((u32)(p - p_lo) < (u32)pch) {
        int a = atomicAdd(&cnt_p[p], 1);
        if (a < CAP_P) csr_p[p * CAP_P + a] = s;
      }
      if ((u32)(s - s_lo) < (u32)sch) {
        int a = atomicAdd(&cnt_s[s], 1);
        if (a < CAP_S) csr_s[s * CAP_S + a] = p;
      }
    }
  }
}

// ---- quad-group PURE mean aggregation (device body) ------------------------
__device__ inline void d_agg_mean(int bid,
    const u16* feat, const int* csr, int cap, const int* cnt,
    u16* out, int n)
{
  int lr = threadIdx.x & 15;
  int grp = threadIdx.x >> 4;           // 0..15
  int gv = bid * 16 + grp;
  if (gv >= n) return;
  int b = gv * cap;
  int c = cnt[gv];
  int cm = min(c, cap);
  float s0=0,s1=0,s2=0,s3=0,s4=0,s5=0,s6=0,s7=0;
  for (int i = 0; i < cm; i += 8) {
    int m = cm - i;
    int idx[8];
#pragma unroll
    for (int u = 0; u < 8; u++) idx[u] = csr[b + i + min(u, m - 1)];
#pragma unroll
    for (int u = 0; u < 8; u++) {
      uint4 v = ((const uint4*)(feat + (size_t)idx[u] * 128))[lr];
      if (u < m) {
        s0 += bf_lo(v.x); s1 += bf_hi(v.x);
        s2 += bf_lo(v.y); s3 += bf_hi(v.y);
        s4 += bf_lo(v.z); s5 += bf_hi(v.z);
        s6 += bf_lo(v.w); s7 += bf_hi(v.w);
      }
    }
  }
  float inv = (c > 0) ? 1.0f / (float)c : 0.0f;
  uint4 o;
  o.x = pack2(s0 * inv, s1 * inv);
  o.y = pack2(s2 * inv, s3 * inv);
  o.z = pack2(s4 * inv, s5 * inv);
  o.w = pack2(s6 * inv, s7 * inv);
  ((uint4*)(out + (size_t)gv * 128))[lr] = o;
}

// ---- paired agg dispatch: problem1 blocks [0,nb1), problem2 after ----------
__global__ __launch_bounds__(256) void agg_pair_k(
    const u16* f1, const int* c1, int cap1, const int* n1v, u16* o1, int n1,
    int nb1,
    const u16* f2, const int* c2, int cap2, const int* n2v, u16* o2, int n2)
{
  int b = blockIdx.x;
  if (b < nb1) d_agg_mean(b, f1, c1, cap1, n1v, o1, n1);
  else         d_agg_mean(b - nb1, f2, c2, cap2, n2v, o2, n2);
}

// ---- K=256 fused GEMM, LDS-staged B (device body, 512-thread blocks) -------
// ldsW: 4096 uint4 (64KB): [h(2)][row(128)][chunk16(16)], chunk^=(row&7).
__device__ inline void d_gemm2_lds(uint4* ldsW, int bid, int nb,
    const u16* A1, const u16* W1, const u16* A2, const u16* W2,
    const float* bias, void* Cout, int M, int doRelu, int outF32)
{
  int tid = threadIdx.x;
  for (int i = tid; i < 2048; i += 512) {
    int row = i >> 4, ch = i & 15;
    int ph = (row << 4) | (ch ^ (row & 7));
    ldsW[ph] = ((const uint4*)W1)[i];
    ldsW[2048 + ph] = ((const uint4*)W2)[i];
  }
  __syncthreads();

  int lane = tid & 63;
  int r = lane & 15, q = lane >> 4;
  int wid = (bid * 512 + tid) >> 6;
  int nw = nb * 8;
  const u16* As[2] = {A1, A2};

  for (int strip = wid; strip * 16 < M; strip += nw) {
    ffrag acc[8];
#pragma unroll
    for (int j = 0; j < 8; j++) acc[j] = (ffrag)0.f;

#pragma unroll 1
    for (int h = 0; h < 2; h++) {
      const u16* arow = As[h] + (size_t)(strip * 16 + r) * 128 + q * 8;
      bfrag a[4];
      a[0] = *(const bfrag*)(arow);
      a[1] = *(const bfrag*)(arow + 32);
      a[2] = *(const bfrag*)(arow + 64);
      a[3] = *(const bfrag*)(arow + 96);
      const uint4* lw = ldsW + (h << 11);
#pragma unroll
      for (int k0 = 0; k0 < 4; k0++) {
        // chunk = k0*4+q, row = j*16+r -> row&7 == r&7 (j-invariant)
        int base = (r << 4) | (((k0 << 2) | q) ^ (r & 7));
#pragma unroll
        for (int j = 0; j < 8; j++) {
          const bfrag* bp = (const bfrag*)&lw[(j << 8) | base];
          acc[j] = __builtin_amdgcn_mfma_f32_16x16x32_bf16(*bp, a[k0], acc[j], 0, 0, 0);
        }
      }
    }

    size_t row = (size_t)(strip * 16 + r);
#pragma unroll
    for (int j = 0; j < 8; j++) {
      int col0 = j * 16 + q * 4;
      float v0 = acc[j][0], v1 = acc[j][1], v2 = acc[j][2], v3 = acc[j][3];
      if (bias) {
        float4 bv = *(const float4*)(bias + col0);
        v0 += bv.x; v1 += bv.y; v2 += bv.z; v3 += bv.w;
      }
      if (doRelu) {
        v0 = fmaxf(v0, 0.f); v1 = fmaxf(v1, 0.f);
        v2 = fmaxf(v2, 0.f); v3 = fmaxf(v3, 0.f);
      }
      if (outF32) {
        *(float4*)((float*)Cout + row * 128 + col0) = make_float4(v0, v1, v2, v3);
      } else {
        ushort4 o;
        o.x = f2bf(v0); o.y = f2bf(v1); o.z = f2bf(v2); o.w = f2bf(v3);
        *(ushort4*)((u16*)Cout + row * 128 + col0) = o;
      }
    }
  }
}

// ---- paired gemm2 dispatch (512 threads): p1 blocks [0,nb1), p2 after ------
__global__ __launch_bounds__(512) void gemm2_pair_k(
    const u16* A1a, const u16* W1a, const u16* A2a, const u16* W2a,
    const float* ba, void* Ca, int Ma, int ra, int oa, int nb1,
    const u16* A1b, const u16* W1b, const u16* A2b, const u16* W2b,
    const float* bb, void* Cb, int Mb, int rb, int ob, int nb2)
{
  __shared__ uint4 ldsW[4096];   // 64KB
  int b = blockIdx.x;
  if (b < nb1)
    d_gemm2_lds(ldsW, b, nb1, A1a, W1a, A2a, W2a, ba, Ca, Ma, ra, oa);
  else
    d_gemm2_lds(ldsW, b - nb1, nb2, A1b, W1b, A2b, W2b, bb, Cb, Mb, rb, ob);
}

// ---------------------------------------------------------------------------

extern "C" void kernel_launch(void* const* d_in, const int* in_sizes, int n_in,
                              void* d_out, int out_size, void* d_ws, size_t ws_size,
                              hipStream_t stream)
{
  const float* song_x = (const float*)d_in[0];
  const int*   pid    = (const int*)d_in[1];
  const int*   e_song = (const int*)d_in[2];
  const int*   e_play = (const int*)d_in[3];
  const float* emb    = (const float*)d_in[4];
  const float* Wl1_sp = (const float*)d_in[5];
  const float* Wr1_sp = (const float*)d_in[6];
  const float* b1_sp  = (const float*)d_in[7];
  const float* Wl1_ps = (const float*)d_in[8];
  const float* Wr1_ps = (const float*)d_in[9];
  const float* b1_ps  = (const float*)d_in[10];
  const float* Wl2_sp = (const float*)d_in[11];
  const float* Wr2_sp = (const float*)d_in[12];
  const float* b2_sp  = (const float*)d_in[13];
  const float* Wl2_ps = (const float*)d_in[14];
  const float* Wr2_ps = (const float*)d_in[15];
  const float* b2_ps  = (const float*)d_in[16];

  const int NS = in_sizes[0] / 128;
  const int NP = in_sizes[1];
  const int E  = in_sizes[2];

  char* w = (char*)d_ws;
  auto alloc = [&](size_t bytes) { char* p = w; w += ws_align(bytes); return p; };
  u16* x_play = (u16*)alloc((size_t)NP * 128 * 2);
  u16* Ms     = (u16*)alloc((size_t)NP * 128 * 2);   // mean_p(...)  [NP,128]
  u16* p1     = (u16*)alloc((size_t)NP * 128 * 2);
  u16* s1     = (u16*)alloc((size_t)NS * 128 * 2);
  u16* xs     = (u16*)alloc((size_t)NS * 128 * 2);
  u16* Msong  = (u16*)alloc((size_t)NS * 128 * 2);   // mean_s(...)  [NS,128]
  u16* Wt     = (u16*)alloc((size_t)8 * 16384 * 2);  // [mat][n][k]
  int* cnt_p  = (int*)alloc(((size_t)NP + NS) * 4);
  int* cnt_s  = cnt_p + NP;
  int* csr_p  = (int*)alloc((size_t)NP * CAP_P * 4);
  int* csr_s  = (int*)alloc((size_t)NS * CAP_S * 4);

  float* s2_out = (float*)d_out;
  float* p2_out = (float*)d_out + (size_t)NS * 128;

  u16* Wt_l1sp = Wt + 0 * 16384;
  u16* Wt_r1sp = Wt + 1 * 16384;
  u16* Wt_l1ps = Wt + 2 * 16384;
  u16* Wt_r1ps = Wt + 3 * 16384;
  u16* Wt_l2sp = Wt + 4 * 16384;
  u16* Wt_r2sp = Wt + 5 * 16384;
  u16* Wt_l2ps = Wt + 6 * 16384;
  u16* Wt_r2ps = Wt + 7 * 16384;

  const int g2S = 512;   // 512 thr: 2 blocks/CU, 16 waves/CU; ~1.5 strips/wave
  const int g2P = 157;   // 1250 strips / 8 waves per block
  const int aggP_b = (NP + 15) / 16, aggS_b = (NS + 15) / 16;
  const int pch = (NP + 7) / 8, sch = (NS + 7) / 8;

  // ---- prep (also zeros degree counters) ----
  prep_k<<<1024, 256, 0, stream>>>(Wl1_sp, Wr1_sp, Wl1_ps, Wr1_ps,
                                   Wl2_sp, Wr2_sp, Wl2_ps, Wr2_ps, Wt,
                                   song_x, xs, NS * 32,
                                   emb, pid, x_play, NP,
                                   cnt_p, NP + NS);

  // ---- CSR build (XCD-chunked atomic wall; standalone) ----
  build_k<<<1024, 256, 0, stream>>>(e_song, e_play, cnt_s, cnt_p,
                                    csr_s, csr_p, E, pch, sch);

  // ---- layer 1: Ms1 = mean_p(xs) || Msong1 = mean_s(x_play) ----
  agg_pair_k<<<aggP_b + aggS_b, 256, 0, stream>>>(
      xs, csr_p, CAP_P, cnt_p, Ms, NP, aggP_b,
      x_play, csr_s, CAP_S, cnt_s, Msong, NS);

  // ---- layer 1: s1 = relu(Msong@Wl1_ps + xs@Wr1_ps + b1_ps)
  //            || p1 = relu(Ms@Wl1_sp + x_play@Wr1_sp + b1_sp) ----
  gemm2_pair_k<<<g2S + g2P, 512, 0, stream>>>(
      Msong, Wt_l1ps, xs, Wt_r1ps, b1_ps, (void*)s1, NS, 1, 0, g2S,
      Ms, Wt_l1sp, x_play, Wt_r1sp, b1_sp, (void*)p1, NP, 1, 0, g2P);

  // ---- layer 2: Ms2 = mean_p(s1) || Msong2 = mean_s(p1) ----
  agg_pair_k<<<aggP_b + aggS_b, 256, 0, stream>>>(
      s1, csr_p, CAP_P, cnt_p, Ms, NP, aggP_b,
      p1, csr_s, CAP_S, cnt_s, Msong, NS);

  // ---- layer 2: s2 = Msong@Wl2_ps + s1@Wr2_ps + b2_ps  (f32)
  //            || p2 = Ms@Wl2_sp + p1@Wr2_sp + b2_sp  (f32) ----
  gemm2_pair_k<<<g2S + g2P, 512, 0, stream>>>(
      Msong, Wt_l2ps, s1, Wt_r2ps, b2_ps, (void*)s2_out, NS, 0, 1, g2S,
      Ms, Wt_l2sp, p1, Wt_r2sp, b2_sp, (void*)p2_out, NP, 0, 1, g2P);
}